// Round 4
// baseline (92.320 us; speedup 1.0000x reference)
//
#include <hip/hip_runtime.h>
#include <hip/hip_bf16.h>

using short8  = __attribute__((ext_vector_type(8))) short;   // 8 bf16 (4 VGPRs)
using floatx4 = __attribute__((ext_vector_type(4))) float;   // 4 fp32 acc

#define B_ROWS 4096
#define NTOT   8192
#define DD     128
#define NTILE  64                    // number of 128-row tiles
#define SQRTC1 1.6986436f            // sqrt(2*log2(e)) — inputs pre-scaled so MFMA yields C1*dot
#define E2f    7.389056098930650f    // exp(2): diagonal self-term to subtract
#define LN2f   0.6931471805599453f   // 2p = d' * ln2  (d' = C1 * p)

// async global->LDS DMA, 16B/lane; LDS dest is wave-uniform base + lane*16
#define GLOAD_LDS16(gptr, lptr)                                                          \
    __builtin_amdgcn_global_load_lds((const __attribute__((address_space(1))) void*)(gptr), \
                                     (__attribute__((address_space(3))) void*)(lptr), 16, 0, 0)

// ---------------- kernel 1: L2-normalize rows, scale by sqrt(C1), cast bf16 ----------------
__global__ __launch_bounds__(256) void nrm_kernel(const float* __restrict__ zi,
                                                  const float* __restrict__ zj,
                                                  __hip_bfloat16* __restrict__ zb) {
    int tid  = threadIdx.x;
    int wave = tid >> 6, lane = tid & 63;
    int row  = blockIdx.x * 4 + wave;
    const float* src = (row < B_ROWS) ? (zi + (size_t)row * DD)
                                      : (zj + (size_t)(row - B_ROWS) * DD);
    float2 v = *(const float2*)(src + lane * 2);
    float s = v.x * v.x + v.y * v.y;
    #pragma unroll
    for (int m = 1; m <= 32; m <<= 1) s += __shfl_xor(s, m, 64);
    float scale = SQRTC1 / fmaxf(sqrtf(s), 1e-12f);
    __hip_bfloat16* dst = zb + (size_t)row * DD + lane * 2;
    dst[0] = __float2bfloat16(v.x * scale);
    dst[1] = __float2bfloat16(v.y * scale);
}

// ---------------- kernel 2: triangular fused sim-GEMM + row/col exp2 sums ----------------
// 2080 blocks = upper-triangle pairs (bi<=bj) of 64 row-tiles (128 rows each).
// Block: 256 thr = 4 waves; wave owns 32 A-rows (af[2][4] = 32 VGPR, no spill).
// B tile (128 cols x K=128, 32 KB) DMA'd once; ONE barrier; 8 col-subtiles.
// Each exp2 value credits its row-sum (always) and its col-sum (off-diag blocks),
// halving both MFMA and exp2 work vs the full matrix.
// lp2 layout [slot(64)][row(8192)]: block (bi,bj) row-sums -> lp2[bj][bi*128+..],
// col-sums -> lp2[bi][bj*128+..]; every (slot,row) written exactly once.
__global__ __launch_bounds__(256, 4) void sim_kernel(const __hip_bfloat16* __restrict__ zbf,
                                                     float* __restrict__ lp2) {
    __shared__ uint4 ldsB[2048];      // [k16chunk(16)][col(128)] = 32 KB
    __shared__ float csum[4][128];    // per-wave col partials
    __shared__ float rsum[128];       // row partials for coalesced flush
    const short* zs = (const short*)zbf;

    int tid = threadIdx.x;
    int w = tid >> 6, lane = tid & 63;
    int q = lane >> 4, n16 = lane & 15;

    // decode blockIdx.x -> (bi, bj), bi<=bj over NTILE=64  (offset(a)=a*64-a(a-1)/2)
    int idx = blockIdx.x;
    int a = (int)((129.0f - sqrtf(16641.0f - 8.0f * (float)idx)) * 0.5f);
    while ((a + 1) * 64 - ((a + 1) * a) / 2 <= idx) ++a;
    while (a * 64 - (a * (a - 1)) / 2 > idx) --a;
    int bi = a, bj = a + (idx - (a * 64 - (a * (a - 1)) / 2));
    bool offdiag = (bi != bj);

    // ---- stage B tile via DMA: chunk c2 = tid+256*rr -> [kc8 = c2>>7][col = c2&127]
    {
        int col = tid & 127, kh = tid >> 7;
        const short* g = zs + (size_t)(bj * 128 + col) * DD + kh * 8;
        #pragma unroll
        for (int rr = 0; rr < 8; ++rr)
            GLOAD_LDS16(g + rr * 16, &ldsB[tid + 256 * rr]);
    }
    // ---- A fragments: rows bi*128 + w*32 + rs*16 + n16; layout m=lane&15, k=q*8+j
    short8 af[2][4];
    #pragma unroll
    for (int rs = 0; rs < 2; ++rs) {
        const short* ap = zs + (size_t)(bi * 128 + w * 32 + rs * 16 + n16) * DD + q * 8;
        #pragma unroll
        for (int kc = 0; kc < 4; ++kc) af[rs][kc] = *(const short8*)(ap + kc * 32);
    }
    __syncthreads();   // drains DMA + A loads; the ONLY pre-epilogue barrier

    float rl[2][4];
    #pragma unroll
    for (int rs = 0; rs < 2; ++rs)
        #pragma unroll
        for (int r = 0; r < 4; ++r) rl[rs][r] = 0.f;

    #pragma unroll
    for (int st = 0; st < 8; ++st) {
        floatx4 acc[2] = {(floatx4){0.f,0.f,0.f,0.f}, (floatx4){0.f,0.f,0.f,0.f}};
        #pragma unroll
        for (int kc = 0; kc < 4; ++kc) {
            // B frag: col = st*16+n16, 16B k-chunk = kc*4+q
            short8 bf = *(const short8*)&ldsB[(kc * 4 + q) * 128 + st * 16 + n16];
            acc[0] = __builtin_amdgcn_mfma_f32_16x16x32_bf16(af[0][kc], bf, acc[0], 0, 0, 0);
            acc[1] = __builtin_amdgcn_mfma_f32_16x16x32_bf16(af[1][kc], bf, acc[1], 0, 0, 0);
        }
        // exp2 epilogue (C layout: row = q*4+r, col = n16)
        float e[2][4];
        #pragma unroll
        for (int rs = 0; rs < 2; ++rs)
            #pragma unroll
            for (int r = 0; r < 4; ++r) {
                e[rs][r] = __builtin_amdgcn_exp2f(acc[rs][r]);
                rl[rs][r] += e[rs][r];
            }
        if (offdiag) {
            // col partial over this wave's 32 rows: sum regs, then over q-groups
            float cp = ((e[0][0] + e[0][1]) + (e[0][2] + e[0][3]))
                     + ((e[1][0] + e[1][1]) + (e[1][2] + e[1][3]));
            cp += __shfl_xor(cp, 16, 64);
            cp += __shfl_xor(cp, 32, 64);
            if (q == 0) csum[w][st * 16 + n16] = cp;
        }
    }

    // row sums: reduce over the 16 col-lanes, park in LDS for coalesced flush
    #pragma unroll
    for (int rs = 0; rs < 2; ++rs)
        #pragma unroll
        for (int r = 0; r < 4; ++r) {
            float v = rl[rs][r];
            v += __shfl_xor(v, 1, 64);
            v += __shfl_xor(v, 2, 64);
            v += __shfl_xor(v, 4, 64);
            v += __shfl_xor(v, 8, 64);
            if (n16 == 0) rsum[w * 32 + rs * 16 + q * 4 + r] = v;
        }
    __syncthreads();
    if (tid < 128) {
        lp2[(size_t)bj * NTOT + bi * 128 + tid] = rsum[tid];
        if (offdiag)
            lp2[(size_t)bi * NTOT + bj * 128 + tid] =
                (csum[0][tid] + csum[1][tid]) + (csum[2][tid] + csum[3][tid]);
    }
}

// ---------------- kernel 3: finalize ----------------
// loss_i = -d'*ln2 + ln(sum_exp2 - e^2); mean via block reduce + 32 atomics
__global__ __launch_bounds__(256) void fin_kernel(const __hip_bfloat16* __restrict__ zbf,
                                                  const float* __restrict__ lp2,
                                                  float* __restrict__ out) {
    __shared__ float red[256];
    int row = blockIdx.x * 256 + threadIdx.x;

    float l = 0.f;
    #pragma unroll
    for (int s = 0; s < 64; ++s) l += lp2[(size_t)s * NTOT + row];

    const __hip_bfloat162* a = (const __hip_bfloat162*)(zbf + (size_t)row * DD);
    const __hip_bfloat162* b = (const __hip_bfloat162*)(zbf + (size_t)(row ^ B_ROWS) * DD);
    float d = 0.f;
    #pragma unroll
    for (int i = 0; i < 64; ++i) {
        float2 av = __bfloat1622float2(a[i]);
        float2 bv = __bfloat1622float2(b[i]);
        d += av.x * bv.x + av.y * bv.y;
    }

    float loss = -d * LN2f + logf(l - E2f);
    red[threadIdx.x] = loss;
    __syncthreads();
    #pragma unroll
    for (int s = 128; s > 0; s >>= 1) {
        if (threadIdx.x < s) red[threadIdx.x] += red[threadIdx.x + s];
        __syncthreads();
    }
    if (threadIdx.x == 0) atomicAdd(out, red[0] * (1.0f / (float)NTOT));
}

extern "C" void kernel_launch(void* const* d_in, const int* in_sizes, int n_in,
                              void* d_out, int out_size, void* d_ws, size_t ws_size,
                              hipStream_t stream) {
    const float* zi = (const float*)d_in[0];
    const float* zj = (const float*)d_in[1];
    float* out = (float*)d_out;

    __hip_bfloat16* zb = (__hip_bfloat16*)d_ws;                     // 2 MB
    float* lp2 = (float*)((char*)d_ws + (size_t)NTOT * DD * 2);     // 2 MB  [64][8192]

    hipMemsetAsync(d_out, 0, sizeof(float), stream);
    nrm_kernel<<<NTOT / 4, 256, 0, stream>>>(zi, zj, zb);
    sim_kernel<<<2080, 256, 0, stream>>>(zb, lp2);
    fin_kernel<<<NTOT / 256, 256, 0, stream>>>(zb, lp2, out);
}